// Round 1
// baseline (1005.924 us; speedup 1.0000x reference)
//
#include <hip/hip_runtime.h>
#include <stdint.h>

// SemsegCDRLink: 2D->3D gather + 3x (masked sparse conv K=27 -> BN -> ReLU)
// Strategy R0: bf16 MFMA dense-over-k gather-GEMM, f32 accum, two-pass BN.

constexpr int NPT = 200000;   // N voxels
constexpr int KNB = 27;       // kernel taps
constexpr int NLNK = 250000;

typedef unsigned short u16;
typedef __attribute__((ext_vector_type(8))) short     bf16x8;
typedef __attribute__((ext_vector_type(8))) unsigned short u16x8;
typedef __attribute__((ext_vector_type(4))) float     f32x4;

static __device__ __forceinline__ u16 f2bf(float f){
  unsigned int u = __float_as_uint(f);
  unsigned int r = (u + 0x7fffu + ((u >> 16) & 1u)) >> 16;
  return (u16)r;
}
static __device__ __forceinline__ float bf2f(u16 u){
  return __uint_as_float(((unsigned int)u) << 16);
}

// ---------------------------------------------------------------- mask dtype
// nbr_mask is numpy bool -> pushed either as uint8 (1B) or int32 (4B).
// Reading the first 64 int32 words is safe under both interpretations
// (256 bytes << 27*N bytes). If dtype is int32, every word is 0 or 1.
__global__ void detect_mask_kernel(const int* __restrict__ m32, int* __restrict__ flag){
  if (threadIdx.x == 0 && blockIdx.x == 0){
    int ok = 1;
    for (int i = 0; i < 64; ++i){ int v = m32[i]; if (v != 0 && v != 1) ok = 0; }
    *flag = ok;   // 1 => int32 masks, 0 => uint8 masks
  }
}

// ------------------------------------------------- feat_2d transpose to NHWC
// in: [V][B][C=64][H=120][W=160] f32   out: [V][B][H][W][C=64] bf16
__global__ __launch_bounds__(256) void transpose2d_kernel(const float* __restrict__ in,
                                                          u16* __restrict__ out){
  __shared__ float tile[64][33];
  int bid = blockIdx.x;
  int wt = bid % 5;  int rest = bid / 5;
  int h  = rest % 120; rest /= 120;
  int b  = rest % 4;  int v = rest / 4;
  int w0 = wt * 32;
  int tx = threadIdx.x & 31;   // w within tile
  int ty = threadIdx.x >> 5;   // 0..7
  const float* ip = in + ((size_t)(v*4 + b) * 64) * 19200 + h * 160 + w0;
  #pragma unroll
  for (int cc = 0; cc < 8; ++cc){
    int c = cc * 8 + ty;
    tile[c][tx] = ip[(size_t)c * 19200 + tx];
  }
  __syncthreads();
  u16* op = out + (((size_t)(v*4 + b) * 120 + h) * 160 + w0) * 64;
  int c = threadIdx.x & 63;
  int wg = threadIdx.x >> 6;   // 0..3
  #pragma unroll
  for (int i = 0; i < 8; ++i){
    int w = wg + i * 4;
    op[(size_t)w * 64 + c] = f2bf(tile[c][w]);
  }
}

// ------------------------------------------------------------ weight reshape
// src: [K][cin][cout] f32  ->  dst: [K][cout][cin] bf16
__global__ void wconvert_kernel(const float* __restrict__ src, u16* __restrict__ dst,
                                int cin, int cout){
  int gid = blockIdx.x * 256 + threadIdx.x;
  int percm = cin * cout;
  int tot = KNB * percm;
  if (gid >= tot) return;
  int k  = gid / percm;
  int r  = gid - k * percm;
  int co = r / cin;
  int ci = r - co * cin;
  dst[gid] = f2bf(src[k * percm + ci * cout + co]);
}

// --------------------------------------------------------------- 2D->3D gather
// X0[cmo[i]][v*64 + c] = val * ft[v][b][h][w][c]
__global__ void stage_a_kernel(const u16* __restrict__ ft, const int* __restrict__ links,
                               const int* __restrict__ cmi, const int* __restrict__ cmo,
                               u16* __restrict__ x0){
  int gid = blockIdx.x * 256 + threadIdx.x;
  if (gid >= NPT * 3) return;
  int i = gid / 3;
  int v = gid - i * 3;
  int outr = cmo[i];
  int l    = cmi[i];
  int b  = links[l*12 + v];
  int h  = links[l*12 + 3 + v];
  int w  = links[l*12 + 6 + v];
  int vl = links[l*12 + 9 + v];
  u16* dst = x0 + (size_t)outr * 192 + v * 64;
  if (vl){
    const u16* src = ft + (((size_t)(v*4 + b) * 120 + h) * 160 + w) * 64;
    #pragma unroll
    for (int j = 0; j < 8; ++j) ((u16x8*)dst)[j] = ((const u16x8*)src)[j];
  } else {
    u16x8 z = {};
    #pragma unroll
    for (int j = 0; j < 8; ++j) ((u16x8*)dst)[j] = z;
  }
}

// ------------------------------------------------------------- f32->bf16 copy
__global__ void f3convert_kernel(const float* __restrict__ src, u16* __restrict__ dst){
  long gid = (long)blockIdx.x * 256 + threadIdx.x;
  long tot8 = (long)NPT * 96 / 8;
  if (gid >= tot8) return;
  long e = gid * 8;
  #pragma unroll
  for (int j = 0; j < 8; ++j) dst[e + j] = f2bf(src[e + j]);
}

// ------------------------------------------------------------------ conv core
// Dense-over-k masked gather GEMM.  Block: 256 thr = 4 waves, 128 rows.
// Wave w owns rows [m0+32w, m0+32w+32): 2 rowblocks x (COUT/16) MFMA tiles.
// W[k] staged to LDS as [cout][cin+8] bf16 (pad -> 2-way conflict b128 reads).
// A fragments gathered directly from global, mask-predicated.
template<int CIN, int COUT, bool CONCAT, bool F32OUT>
__global__ __launch_bounds__(256)
void conv_kernel(const u16* __restrict__ x0, const u16* __restrict__ x1,
                 const u16* __restrict__ wt, const int* __restrict__ in_idx,
                 const uint8_t* __restrict__ mu8, const int* __restrict__ mi32,
                 const int* __restrict__ flagp, void* __restrict__ outp){
  constexpr int CINP = CIN + 8;
  constexpr int NCB  = COUT / 16;
  constexpr int NKC  = CIN / 32;
  __shared__ __align__(16) u16 wlds[COUT * CINP];

  const int tid  = threadIdx.x;
  const int lane = tid & 63;
  const int wv   = tid >> 6;
  const int m0   = blockIdx.x * 128;
  const int r16  = lane & 15;
  const int kgrp = lane >> 4;
  const int fInt = *flagp;

  f32x4 acc[2][NCB];
  #pragma unroll
  for (int rb = 0; rb < 2; ++rb)
    #pragma unroll
    for (int cb = 0; cb < NCB; ++cb) acc[rb][cb] = (f32x4)0.0f;

  for (int k = 0; k < KNB; ++k){
    // stage W[k] -> LDS
    const u16* wsrc = wt + (size_t)k * (CIN * COUT);
    #pragma unroll
    for (int e = tid * 8; e < CIN * COUT; e += 256 * 8){
      int cout = e / CIN;
      int ci   = e - cout * CIN;
      *(u16x8*)&wlds[cout * CINP + ci] = *(const u16x8*)&wsrc[e];
    }
    __syncthreads();

    int ids[2]; bool val[2];
    #pragma unroll
    for (int rb = 0; rb < 2; ++rb){
      int row  = m0 + wv * 32 + rb * 16 + r16;
      int rowc = row < NPT ? row : NPT - 1;
      ids[rb] = in_idx[k * NPT + rowc];
      int mv;
      if (fInt) mv = mi32[k * NPT + rowc];
      else      mv = (int)mu8[k * NPT + rowc];
      val[rb] = (mv != 0);
    }

    #pragma unroll
    for (int kc = 0; kc < NKC; ++kc){
      int ci0 = kc * 32 + kgrp * 8;
      bf16x8 a[2];
      #pragma unroll
      for (int rb = 0; rb < 2; ++rb){
        const u16* ap;
        if (CONCAT) ap = (ci0 < 96) ? (x0 + (size_t)ids[rb] * 96 + ci0)
                                    : (x1 + (size_t)ids[rb] * 96 + (ci0 - 96));
        else        ap = x0 + (size_t)ids[rb] * CIN + ci0;
        bf16x8 z = {};
        a[rb] = val[rb] ? *(const bf16x8*)ap : z;
      }
      #pragma unroll
      for (int cb = 0; cb < NCB; ++cb){
        bf16x8 b = *(const bf16x8*)&wlds[(cb * 16 + r16) * CINP + ci0];
        acc[0][cb] = __builtin_amdgcn_mfma_f32_16x16x32_bf16(a[0], b, acc[0][cb], 0, 0, 0);
        acc[1][cb] = __builtin_amdgcn_mfma_f32_16x16x32_bf16(a[1], b, acc[1][cb], 0, 0, 0);
      }
    }
    __syncthreads();
  }

  // epilogue: C/D layout col = lane&15, row = (lane>>4)*4 + j  [m89-verified]
  #pragma unroll
  for (int rb = 0; rb < 2; ++rb){
    #pragma unroll
    for (int cb = 0; cb < NCB; ++cb){
      int cout = cb * 16 + r16;
      #pragma unroll
      for (int j = 0; j < 4; ++j){
        int row = m0 + wv * 32 + rb * 16 + kgrp * 4 + j;
        if (row < NPT){
          float v = acc[rb][cb][j];
          if (F32OUT) ((float*)outp)[(size_t)row * COUT + cout] = v;
          else        ((u16*)outp)[(size_t)row * COUT + cout] = f2bf(v);
        }
      }
    }
  }
}

// ------------------------------------------------------------------ BN stats
template<int CCH, bool ISF32>
__global__ __launch_bounds__(256) void stats_kernel(const void* __restrict__ xp,
                                                    float* __restrict__ st){
  constexpr int RSTEP = (CCH == 64) ? 4 : 2;
  constexpr int ACT   = CCH * RSTEP;
  __shared__ float shS[CCH], shQ[CCH];
  int tid = threadIdx.x;
  if (tid < CCH){ shS[tid] = 0.f; shQ[tid] = 0.f; }
  __syncthreads();
  if (tid < ACT){
    int c = tid % CCH;
    int g = tid / CCH;
    float s = 0.f, q = 0.f;
    for (long r = (long)blockIdx.x * RSTEP + g; r < NPT; r += (long)gridDim.x * RSTEP){
      float v;
      if (ISF32) v = ((const float*)xp)[r * CCH + c];
      else       v = bf2f(((const u16*)xp)[r * CCH + c]);
      s += v; q += v * v;
    }
    atomicAdd(&shS[c], s); atomicAdd(&shQ[c], q);
  }
  __syncthreads();
  if (tid < CCH){
    atomicAdd(&st[tid], shS[tid]);
    atomicAdd(&st[CCH + tid], shQ[tid]);
  }
}

// --------------------------------------------------------------- BN + ReLU
template<int CCH, bool ISF32>
__global__ void bnrelu_kernel(void* __restrict__ xp, const float* __restrict__ st,
                              const float* __restrict__ gg, const float* __restrict__ bb){
  const float invN = 1.0f / (float)NPT;
  long tot8 = (long)NPT * CCH / 8;
  for (long e8 = (long)blockIdx.x * 256 + threadIdx.x; e8 < tot8; e8 += (long)gridDim.x * 256){
    long e = e8 * 8;
    int c0 = (int)(e % CCH);
    #pragma unroll
    for (int j = 0; j < 8; ++j){
      int c = c0 + j;
      float mu  = st[c] * invN;
      float var = st[CCH + c] * invN - mu * mu;
      float rs  = rsqrtf(var + 1e-5f);
      float x;
      if (ISF32) x = ((float*)xp)[e + j];
      else       x = bf2f(((u16*)xp)[e + j]);
      float y = gg[c] * (x - mu) * rs + bb[c];
      y = y > 0.f ? y : 0.f;
      if (ISF32) ((float*)xp)[e + j] = y;
      else       ((u16*)xp)[e + j] = f2bf(y);
    }
  }
}

// =====================================================================
extern "C" void kernel_launch(void* const* d_in, const int* in_sizes, int n_in,
                              void* d_out, int out_size, void* d_ws, size_t ws_size,
                              hipStream_t stream){
  const float* feat2d = (const float*)d_in[0];
  const float* feat3d = (const float*)d_in[1];
  const int*   links  = (const int*)d_in[2];
  const int*   cmi    = (const int*)d_in[3];
  const int*   cmo    = (const int*)d_in[4];
  const int*   inidx  = (const int*)d_in[5];
  const void*  mask   = d_in[6];
  const float* W1 = (const float*)d_in[7];
  const float* g1 = (const float*)d_in[8];
  const float* b1 = (const float*)d_in[9];
  const float* W2 = (const float*)d_in[10];
  const float* g2 = (const float*)d_in[11];
  const float* b2 = (const float*)d_in[12];
  const float* W3 = (const float*)d_in[13];
  const float* g3 = (const float*)d_in[14];
  const float* b3 = (const float*)d_in[15];

  // workspace layout (bytes), total ~108.3 MB:
  //  [0, 76.8M)        X0 (N,192)bf16 ; after conv1: ZA (N,96)bf16 @0, F3 (N,96)bf16 @38.4M
  //  [76.8M, 106.3M)   ftrans (29.5M) ; after stage_a: Z1/H1 (N,64)bf16 (25.6M)
  //  [106.3M, 108.28M) Wt1|Wt2|Wt3 bf16
  //  [108.28M, ...)    stats (512 f32) + flag
  char* ws = (char*)d_ws;
  u16* X0 = (u16*)(ws + 0);
  u16* ZA = (u16*)(ws + 0);
  u16* F3 = (u16*)(ws + 38400000);
  u16* Z1 = (u16*)(ws + 76800000);
  u16* FT = (u16*)(ws + 76800000);
  u16* WT1 = (u16*)(ws + 106291200);
  u16* WT2 = WT1 + 27 * 192 * 64;
  u16* WT3 = WT2 + 27 * 64 * 96;
  float* ST  = (float*)(ws + 108281856);
  float* ST1 = ST;            // 128 floats
  float* ST2 = ST + 128;      // 192 floats
  float* ST3 = ST + 320;      // 192 floats
  int*   FLAG = (int*)(ST + 512);

  hipMemsetAsync(ST, 0, 513 * sizeof(float), stream);
  detect_mask_kernel<<<1, 64, 0, stream>>>((const int*)mask, FLAG);
  transpose2d_kernel<<<7200, 256, 0, stream>>>(feat2d, FT);
  wconvert_kernel<<<(27*192*64 + 255)/256, 256, 0, stream>>>(W1, WT1, 192, 64);
  wconvert_kernel<<<(27*64*96  + 255)/256, 256, 0, stream>>>(W2, WT2, 64, 96);
  wconvert_kernel<<<(27*192*96 + 255)/256, 256, 0, stream>>>(W3, WT3, 192, 96);
  stage_a_kernel<<<(NPT*3 + 255)/256, 256, 0, stream>>>(FT, links, cmi, cmo, X0);

  const int nblk = (NPT + 127) / 128;
  const uint8_t* m8 = (const uint8_t*)mask;
  const int* m32 = (const int*)mask;

  // layer 1: X0 (N,192) -> Z1 (N,64)
  conv_kernel<192, 64, false, false><<<nblk, 256, 0, stream>>>(X0, nullptr, WT1, inidx, m8, m32, FLAG, Z1);
  stats_kernel<64, false><<<512, 256, 0, stream>>>(Z1, ST1);
  bnrelu_kernel<64, false><<<2048, 256, 0, stream>>>(Z1, ST1, g1, b1);

  f3convert_kernel<<<((NPT*96/8) + 255)/256, 256, 0, stream>>>(feat3d, F3);

  // layer 2: H1 (N,64) -> ZA (N,96)
  conv_kernel<64, 96, false, false><<<nblk, 256, 0, stream>>>(Z1, nullptr, WT2, inidx, m8, m32, FLAG, ZA);
  stats_kernel<96, false><<<512, 256, 0, stream>>>(ZA, ST2);
  bnrelu_kernel<96, false><<<2048, 256, 0, stream>>>(ZA, ST2, g2, b2);

  // layer 3: [F3 | H2] (N,192) -> d_out (N,96) f32
  conv_kernel<192, 96, true, true><<<nblk, 256, 0, stream>>>(F3, ZA, WT3, inidx, m8, m32, FLAG, d_out);
  stats_kernel<96, true><<<512, 256, 0, stream>>>(d_out, ST3);
  bnrelu_kernel<96, true><<<2048, 256, 0, stream>>>(d_out, ST3, g3, b3);
}

// Round 2
// 923.121 us; speedup vs baseline: 1.0897x; 1.0897x over previous
//
#include <hip/hip_runtime.h>
#include <stdint.h>

// SemsegCDRLink R2: 32x32x16 MFMA, 64 rows/wave, fragment-order W in LDS,
// register-prefetched W staging, BN stats fused into conv epilogue.

constexpr int NPT = 200000;   // N voxels
constexpr int KNB = 27;       // kernel taps

typedef unsigned short u16;
typedef __attribute__((ext_vector_type(8))) short     bf16x8;
typedef __attribute__((ext_vector_type(8))) unsigned short u16x8;
typedef __attribute__((ext_vector_type(16))) float    f32x16;

static __device__ __forceinline__ u16 f2bf(float f){
  unsigned int u = __float_as_uint(f);
  unsigned int r = (u + 0x7fffu + ((u >> 16) & 1u)) >> 16;
  return (u16)r;
}
static __device__ __forceinline__ float bf2f(u16 u){
  return __uint_as_float(((unsigned int)u) << 16);
}

// ---------------------------------------------------------------- mask dtype
__global__ void detect_mask_kernel(const int* __restrict__ m32, int* __restrict__ flag){
  if (threadIdx.x == 0 && blockIdx.x == 0){
    int ok = 1;
    for (int i = 0; i < 64; ++i){ int v = m32[i]; if (v != 0 && v != 1) ok = 0; }
    *flag = ok;   // 1 => int32 masks, 0 => uint8 masks
  }
}

// ------------------------------------------------- feat_2d transpose to NHWC
// in: [V][B][C=64][H=120][W=160] f32   out: [V][B][H][W][C=64] bf16
__global__ __launch_bounds__(256) void transpose2d_kernel(const float* __restrict__ in,
                                                          u16* __restrict__ out){
  __shared__ float tile[64][33];
  int bid = blockIdx.x;
  int wt = bid % 5;  int rest = bid / 5;
  int h  = rest % 120; rest /= 120;
  int b  = rest % 4;  int v = rest / 4;
  int w0 = wt * 32;
  int tx = threadIdx.x & 31;
  int ty = threadIdx.x >> 5;
  const float* ip = in + ((size_t)(v*4 + b) * 64) * 19200 + h * 160 + w0;
  #pragma unroll
  for (int cc = 0; cc < 8; ++cc){
    int c = cc * 8 + ty;
    tile[c][tx] = ip[(size_t)c * 19200 + tx];
  }
  __syncthreads();
  u16* op = out + (((size_t)(v*4 + b) * 120 + h) * 160 + w0) * 64;
  int c = threadIdx.x & 63;
  int wg = threadIdx.x >> 6;
  #pragma unroll
  for (int i = 0; i < 8; ++i){
    int w = wg + i * 4;
    op[(size_t)w * 64 + c] = f2bf(tile[c][w]);
  }
}

// ------------------------------------------------------------ weight reshape
// src: [K][cin][cout] f32 -> dst fragment order:
// dst[ k*WELE + ((ks*NCB+cb)*512) + lane*8 + e ] = W[k][ks*16+(lane>>5)*8+e][cb*32+(lane&31)]
__global__ void wconvert_kernel(const float* __restrict__ src, u16* __restrict__ dst,
                                int cin, int cout){
  int gid = blockIdx.x * 256 + threadIdx.x;
  int wele = cin * cout;
  int tot = KNB * wele;
  if (gid >= tot) return;
  int ncb = cout / 32;
  int nks = cin / 16;
  int e    = gid & 7;
  int lane = (gid >> 3) & 63;
  int f    = gid >> 9;
  int cb   = f % ncb;  f /= ncb;
  int ks   = f % nks;
  int k    = f / nks;
  int ci = ks * 16 + (lane >> 5) * 8 + e;
  int co = cb * 32 + (lane & 31);
  dst[gid] = f2bf(src[((size_t)k * cin + ci) * cout + co]);
}

// --------------------------------------------------------------- 2D->3D gather
__global__ void stage_a_kernel(const u16* __restrict__ ft, const int* __restrict__ links,
                               const int* __restrict__ cmi, const int* __restrict__ cmo,
                               u16* __restrict__ x0){
  int gid = blockIdx.x * 256 + threadIdx.x;
  if (gid >= NPT * 3) return;
  int i = gid / 3;
  int v = gid - i * 3;
  int outr = cmo[i];
  int l    = cmi[i];
  int b  = links[l*12 + v];
  int h  = links[l*12 + 3 + v];
  int w  = links[l*12 + 6 + v];
  int vl = links[l*12 + 9 + v];
  u16* dst = x0 + (size_t)outr * 192 + v * 64;
  if (vl){
    const u16* src = ft + (((size_t)(v*4 + b) * 120 + h) * 160 + w) * 64;
    #pragma unroll
    for (int j = 0; j < 8; ++j) ((u16x8*)dst)[j] = ((const u16x8*)src)[j];
  } else {
    u16x8 z = {};
    #pragma unroll
    for (int j = 0; j < 8; ++j) ((u16x8*)dst)[j] = z;
  }
}

// ------------------------------------------------------------- f32->bf16 copy
__global__ void f3convert_kernel(const float* __restrict__ src, u16* __restrict__ dst){
  long gid = (long)blockIdx.x * 256 + threadIdx.x;
  long tot8 = (long)NPT * 96 / 8;
  if (gid >= tot8) return;
  long e = gid * 8;
  #pragma unroll
  for (int j = 0; j < 8; ++j) dst[e + j] = f2bf(src[e + j]);
}

// ------------------------------------------------------------------ conv core
// Block: 256 thr = 4 waves, 256 rows (64 rows/wave, 2x 32-row MFMA tiles).
// W[k] in LDS in fragment order (contiguous per-lane b128 reads, no conflicts).
// W[k+1] prefetched into registers during tap-k compute.
// BN stats (sum, sumsq) accumulated from f32 acc in epilogue.
template<int CIN, int COUT, bool CONCAT, bool F32OUT>
__global__ __launch_bounds__(256)
void conv_kernel(const u16* __restrict__ x0, const u16* __restrict__ x1,
                 const u16* __restrict__ wt, const int* __restrict__ in_idx,
                 const uint8_t* __restrict__ mu8, const int* __restrict__ mi32,
                 const int* __restrict__ flagp, void* __restrict__ outp,
                 float* __restrict__ st){
  constexpr int NCB  = COUT / 32;
  constexpr int NKS  = CIN / 16;
  constexpr int WELE = CIN * COUT;
  constexpr int SEGS = WELE / 2048;
  __shared__ __align__(16) u16 wlds[WELE];
  __shared__ float shS[COUT], shQ[COUT];

  const int tid   = threadIdx.x;
  const int lane  = tid & 63;
  const int wv    = tid >> 6;
  const int l31   = lane & 31;
  const int khalf = lane >> 5;
  const int m0    = blockIdx.x * 256;
  const int fInt  = *flagp;

  f32x16 acc[2][NCB];
  #pragma unroll
  for (int rt = 0; rt < 2; ++rt)
    #pragma unroll
    for (int cb = 0; cb < NCB; ++cb) acc[rt][cb] = (f32x16)0.0f;

  u16x8 wpre[SEGS];
  #pragma unroll
  for (int s = 0; s < SEGS; ++s) wpre[s] = *(const u16x8*)&wt[tid*8 + s*2048];
  #pragma unroll
  for (int s = 0; s < SEGS; ++s) *(u16x8*)&wlds[tid*8 + s*2048] = wpre[s];
  __syncthreads();

  for (int k = 0; k < KNB; ++k){
    // prefetch next tap's weights into registers (latency hidden by compute)
    if (k + 1 < KNB){
      const u16* wn = wt + (size_t)(k+1) * WELE;
      #pragma unroll
      for (int s = 0; s < SEGS; ++s) wpre[s] = *(const u16x8*)&wn[tid*8 + s*2048];
    }

    int ids[2]; bool val[2];
    #pragma unroll
    for (int rt = 0; rt < 2; ++rt){
      int row  = m0 + wv * 64 + rt * 32 + l31;
      int rowc = row < NPT ? row : NPT - 1;
      ids[rt] = in_idx[k * NPT + rowc];
      int mv;
      if (fInt) mv = mi32[k * NPT + rowc];
      else      mv = (int)mu8[k * NPT + rowc];
      val[rt] = (mv != 0);
    }

    #pragma unroll
    for (int ks = 0; ks < NKS; ++ks){
      const int ci0 = ks * 16 + khalf * 8;
      bf16x8 a[2];
      #pragma unroll
      for (int rt = 0; rt < 2; ++rt){
        const u16* ap;
        if (CONCAT) ap = (ci0 < 96) ? (x0 + (size_t)ids[rt] * 96 + ci0)
                                    : (x1 + (size_t)ids[rt] * 96 + (ci0 - 96));
        else        ap = x0 + (size_t)ids[rt] * CIN + ci0;
        bf16x8 z = {};
        a[rt] = val[rt] ? *(const bf16x8*)ap : z;
      }
      #pragma unroll
      for (int cb = 0; cb < NCB; ++cb){
        bf16x8 b = *(const bf16x8*)&wlds[(ks * NCB + cb) * 512 + lane * 8];
        acc[0][cb] = __builtin_amdgcn_mfma_f32_32x32x16_bf16(a[0], b, acc[0][cb], 0, 0, 0);
        acc[1][cb] = __builtin_amdgcn_mfma_f32_32x32x16_bf16(a[1], b, acc[1][cb], 0, 0, 0);
      }
    }
    __syncthreads();
    if (k + 1 < KNB){
      #pragma unroll
      for (int s = 0; s < SEGS; ++s) *(u16x8*)&wlds[tid*8 + s*2048] = wpre[s];
      __syncthreads();
    }
  }

  // epilogue: C/D layout col = lane&31, row = (r&3) + 8*(r>>2) + 4*(lane>>5)
  if (tid < COUT){ shS[tid] = 0.f; shQ[tid] = 0.f; }
  __syncthreads();

  #pragma unroll
  for (int rt = 0; rt < 2; ++rt){
    #pragma unroll
    for (int cb = 0; cb < NCB; ++cb){
      const int cout = cb * 32 + l31;
      float s = 0.f, q = 0.f;
      #pragma unroll
      for (int r = 0; r < 16; ++r){
        int row = m0 + wv * 64 + rt * 32 + (r & 3) + 8 * (r >> 2) + 4 * khalf;
        if (row < NPT){
          float v = acc[rt][cb][r];
          if (F32OUT) ((float*)outp)[(size_t)row * COUT + cout] = v;
          else        ((u16*)outp)[(size_t)row * COUT + cout] = f2bf(v);
          s += v; q += v * v;
        }
      }
      atomicAdd(&shS[cout], s); atomicAdd(&shQ[cout], q);
    }
  }
  __syncthreads();
  if (tid < COUT){
    atomicAdd(&st[tid],        shS[tid]);
    atomicAdd(&st[COUT + tid], shQ[tid]);
  }
}

// --------------------------------------------------------------- BN + ReLU
template<int CCH, bool ISF32>
__global__ void bnrelu_kernel(void* __restrict__ xp, const float* __restrict__ st,
                              const float* __restrict__ gg, const float* __restrict__ bb){
  const float invN = 1.0f / (float)NPT;
  long tot8 = (long)NPT * CCH / 8;
  for (long e8 = (long)blockIdx.x * 256 + threadIdx.x; e8 < tot8; e8 += (long)gridDim.x * 256){
    long e = e8 * 8;
    int c0 = (int)(e % CCH);
    #pragma unroll
    for (int j = 0; j < 8; ++j){
      int c = c0 + j;
      float mu  = st[c] * invN;
      float var = st[CCH + c] * invN - mu * mu;
      float rs  = rsqrtf(var + 1e-5f);
      float x;
      if (ISF32) x = ((float*)xp)[e + j];
      else       x = bf2f(((u16*)xp)[e + j]);
      float y = gg[c] * (x - mu) * rs + bb[c];
      y = y > 0.f ? y : 0.f;
      if (ISF32) ((float*)xp)[e + j] = y;
      else       ((u16*)xp)[e + j] = f2bf(y);
    }
  }
}

// =====================================================================
extern "C" void kernel_launch(void* const* d_in, const int* in_sizes, int n_in,
                              void* d_out, int out_size, void* d_ws, size_t ws_size,
                              hipStream_t stream){
  const float* feat2d = (const float*)d_in[0];
  const float* feat3d = (const float*)d_in[1];
  const int*   links  = (const int*)d_in[2];
  const int*   cmi    = (const int*)d_in[3];
  const int*   cmo    = (const int*)d_in[4];
  const int*   inidx  = (const int*)d_in[5];
  const void*  mask   = d_in[6];
  const float* W1 = (const float*)d_in[7];
  const float* g1 = (const float*)d_in[8];
  const float* b1 = (const float*)d_in[9];
  const float* W2 = (const float*)d_in[10];
  const float* g2 = (const float*)d_in[11];
  const float* b2 = (const float*)d_in[12];
  const float* W3 = (const float*)d_in[13];
  const float* g3 = (const float*)d_in[14];
  const float* b3 = (const float*)d_in[15];

  // workspace layout (bytes), ~108.3 MB (same budget as R0):
  //  [0, 76.8M)        X0 (N,192)bf16 ; after conv1: ZA (N,96)bf16 @0, F3 @38.4M
  //  [76.8M, 106.3M)   ftrans ; after stage_a: Z1 (N,64)bf16
  //  [106.3M, ...)     Wt1|Wt2|Wt3 bf16, stats, flag
  char* ws = (char*)d_ws;
  u16* X0 = (u16*)(ws + 0);
  u16* ZA = (u16*)(ws + 0);
  u16* F3 = (u16*)(ws + 38400000);
  u16* Z1 = (u16*)(ws + 76800000);
  u16* FT = (u16*)(ws + 76800000);
  u16* WT1 = (u16*)(ws + 106291200);
  u16* WT2 = WT1 + 27 * 192 * 64;
  u16* WT3 = WT2 + 27 * 64 * 96;
  float* ST  = (float*)(ws + 108281856);
  float* ST1 = ST;            // 128 floats (S|Q)
  float* ST2 = ST + 128;      // 192 floats
  float* ST3 = ST + 320;      // 192 floats
  int*   FLAG = (int*)(ST + 512);

  hipMemsetAsync(ST, 0, 513 * sizeof(float), stream);
  detect_mask_kernel<<<1, 64, 0, stream>>>((const int*)mask, FLAG);
  transpose2d_kernel<<<7200, 256, 0, stream>>>(feat2d, FT);
  wconvert_kernel<<<(27*192*64 + 255)/256, 256, 0, stream>>>(W1, WT1, 192, 64);
  wconvert_kernel<<<(27*64*96  + 255)/256, 256, 0, stream>>>(W2, WT2, 64, 96);
  wconvert_kernel<<<(27*192*96 + 255)/256, 256, 0, stream>>>(W3, WT3, 192, 96);
  stage_a_kernel<<<(NPT*3 + 255)/256, 256, 0, stream>>>(FT, links, cmi, cmo, X0);

  const int nblk = (NPT + 255) / 256;
  const uint8_t* m8 = (const uint8_t*)mask;
  const int* m32 = (const int*)mask;

  // layer 1: X0 (N,192) -> Z1 (N,64)
  conv_kernel<192, 64, false, false><<<nblk, 256, 0, stream>>>(X0, nullptr, WT1, inidx, m8, m32, FLAG, Z1, ST1);
  bnrelu_kernel<64, false><<<2048, 256, 0, stream>>>(Z1, ST1, g1, b1);

  f3convert_kernel<<<((NPT*96/8) + 255)/256, 256, 0, stream>>>(feat3d, F3);

  // layer 2: Z1 (N,64) -> ZA (N,96)
  conv_kernel<64, 96, false, false><<<nblk, 256, 0, stream>>>(Z1, nullptr, WT2, inidx, m8, m32, FLAG, ZA, ST2);
  bnrelu_kernel<96, false><<<2048, 256, 0, stream>>>(ZA, ST2, g2, b2);

  // layer 3: [F3 | H2] (N,192) -> d_out (N,96) f32
  conv_kernel<192, 96, true, true><<<nblk, 256, 0, stream>>>(F3, ZA, WT3, inidx, m8, m32, FLAG, d_out, ST3);
  bnrelu_kernel<96, true><<<2048, 256, 0, stream>>>(d_out, ST3, g3, b3);
}

// Round 3
// 896.104 us; speedup vs baseline: 1.1226x; 1.0302x over previous
//
#include <hip/hip_runtime.h>
#include <stdint.h>

// SemsegCDRLink R3: 16x16x32 MFMA, 128 rows/block, W double-buffered in LDS
// (issue-early/write-late, ONE barrier per tap), ids prefetched 1 tap ahead,
// exec-masked valid-skip gathers, layer-3 col-split, fused BN stats.

constexpr int NPT = 200000;   // N voxels
constexpr int KNB = 27;       // kernel taps

typedef unsigned short u16;
typedef __attribute__((ext_vector_type(8))) short     bf16x8;
typedef __attribute__((ext_vector_type(8))) unsigned short u16x8;
typedef __attribute__((ext_vector_type(4))) float     f32x4;

static __device__ __forceinline__ u16 f2bf(float f){
  unsigned int u = __float_as_uint(f);
  unsigned int r = (u + 0x7fffu + ((u >> 16) & 1u)) >> 16;
  return (u16)r;
}
static __device__ __forceinline__ float bf2f(u16 u){
  return __uint_as_float(((unsigned int)u) << 16);
}

// ---------------------------------------------------------------- mask dtype
__global__ void detect_mask_kernel(const int* __restrict__ m32, int* __restrict__ flag){
  if (threadIdx.x == 0 && blockIdx.x == 0){
    int ok = 1;
    for (int i = 0; i < 64; ++i){ int v = m32[i]; if (v != 0 && v != 1) ok = 0; }
    *flag = ok;   // 1 => int32 masks, 0 => uint8 masks
  }
}

// ------------------------------------------------- feat_2d transpose to NHWC
__global__ __launch_bounds__(256) void transpose2d_kernel(const float* __restrict__ in,
                                                          u16* __restrict__ out){
  __shared__ float tile[64][33];
  int bid = blockIdx.x;
  int wt = bid % 5;  int rest = bid / 5;
  int h  = rest % 120; rest /= 120;
  int b  = rest % 4;  int v = rest / 4;
  int w0 = wt * 32;
  int tx = threadIdx.x & 31;
  int ty = threadIdx.x >> 5;
  const float* ip = in + ((size_t)(v*4 + b) * 64) * 19200 + h * 160 + w0;
  #pragma unroll
  for (int cc = 0; cc < 8; ++cc){
    int c = cc * 8 + ty;
    tile[c][tx] = ip[(size_t)c * 19200 + tx];
  }
  __syncthreads();
  u16* op = out + (((size_t)(v*4 + b) * 120 + h) * 160 + w0) * 64;
  int c = threadIdx.x & 63;
  int wg = threadIdx.x >> 6;
  #pragma unroll
  for (int i = 0; i < 8; ++i){
    int w = wg + i * 4;
    op[(size_t)w * 64 + c] = f2bf(tile[c][w]);
  }
}

// ------------------------------------------------------------ weight reshape
// src: [K][cin][coutFull] f32 -> frag order for 16x16x32:
// dst[((k*NKC+kc)*NCB+cb)*512 + lane*8 + e] =
//   W[k][kc*32+(lane>>4)*8+e][cbase + cb*16 + (lane&15)]
__global__ void wconvert_kernel(const float* __restrict__ src, u16* __restrict__ dst,
                                int cin, int coutT, int coutF, int cbase){
  int gid = blockIdx.x * 256 + threadIdx.x;
  int tot = KNB * cin * coutT;
  if (gid >= tot) return;
  int ncb = coutT / 16;
  int nkc = cin / 32;
  int e    = gid & 7;
  int lane = (gid >> 3) & 63;
  int f    = gid >> 9;
  int cb   = f % ncb;  f /= ncb;
  int kc   = f % nkc;
  int k    = f / nkc;
  int ci = kc * 32 + (lane >> 4) * 8 + e;
  int co = cbase + cb * 16 + (lane & 15);
  dst[gid] = f2bf(src[((size_t)k * cin + ci) * coutF + co]);
}

// --------------------------------------------------------------- 2D->3D gather
__global__ void stage_a_kernel(const u16* __restrict__ ft, const int* __restrict__ links,
                               const int* __restrict__ cmi, const int* __restrict__ cmo,
                               u16* __restrict__ x0){
  int gid = blockIdx.x * 256 + threadIdx.x;
  if (gid >= NPT * 3) return;
  int i = gid / 3;
  int v = gid - i * 3;
  int outr = cmo[i];
  int l    = cmi[i];
  int b  = links[l*12 + v];
  int h  = links[l*12 + 3 + v];
  int w  = links[l*12 + 6 + v];
  int vl = links[l*12 + 9 + v];
  u16* dst = x0 + (size_t)outr * 192 + v * 64;
  if (vl){
    const u16* src = ft + (((size_t)(v*4 + b) * 120 + h) * 160 + w) * 64;
    #pragma unroll
    for (int j = 0; j < 8; ++j) ((u16x8*)dst)[j] = ((const u16x8*)src)[j];
  } else {
    u16x8 z = {};
    #pragma unroll
    for (int j = 0; j < 8; ++j) ((u16x8*)dst)[j] = z;
  }
}

// ------------------------------------------------------------- f32->bf16 copy
__global__ void f3convert_kernel(const float* __restrict__ src, u16* __restrict__ dst){
  long gid = (long)blockIdx.x * 256 + threadIdx.x;
  long tot8 = (long)NPT * 96 / 8;
  if (gid >= tot8) return;
  long e = gid * 8;
  #pragma unroll
  for (int j = 0; j < 8; ++j) dst[e + j] = f2bf(src[e + j]);
}

// ------------------------------------------------------------------ conv core
template<int CIN, int COUT_T, bool CONCAT, bool COLSPLIT, bool F32OUT>
__global__ __launch_bounds__(256)
void conv_kernel(const u16* __restrict__ x0, const u16* __restrict__ x1,
                 const u16* __restrict__ wtA, const u16* __restrict__ wtB,
                 const int* __restrict__ in_idx,
                 const uint8_t* __restrict__ mu8, const int* __restrict__ mi32,
                 const int* __restrict__ flagp, void* __restrict__ outp,
                 float* __restrict__ st){
  constexpr int NCB   = COUT_T / 16;
  constexpr int NKC   = CIN / 32;
  constexpr int WELE  = CIN * COUT_T;              // u16 elems per tap
  constexpr int SEGS  = (WELE + 2047) / 2048;
  constexpr int COUTF = COLSPLIT ? COUT_T * 2 : COUT_T;
  __shared__ __align__(16) u16 wlds[2 * WELE];
  __shared__ float shS[COUT_T], shQ[COUT_T];

  const int tid   = threadIdx.x;
  const int lane  = tid & 63;
  const int wv    = tid >> 6;
  const int r16   = lane & 15;
  const int kgrp  = lane >> 4;
  const int bid   = blockIdx.x;
  const int half  = COLSPLIT ? (bid & 1) : 0;
  const int m0    = (COLSPLIT ? (bid >> 1) : bid) * 128;
  const int cbase = half * COUT_T;
  const u16* wt   = (COLSPLIT && half) ? wtB : wtA;
  const int fInt  = *flagp;

  if (tid < COUT_T){ shS[tid] = 0.f; shQ[tid] = 0.f; }

  f32x4 acc[2][NCB];
  #pragma unroll
  for (int rt = 0; rt < 2; ++rt)
    #pragma unroll
    for (int cb = 0; cb < NCB; ++cb) acc[rt][cb] = (f32x4)0.0f;

  int rowc[2];
  #pragma unroll
  for (int rt = 0; rt < 2; ++rt){
    int row = m0 + wv * 32 + rt * 16 + r16;
    rowc[rt] = row < NPT ? row : NPT - 1;
  }

  // prologue: stage W[0] -> wbuf0, load ids/mask[0]
  #pragma unroll
  for (int s = 0; s < SEGS; ++s){
    int off = (tid + s * 256) * 8;
    if (off < WELE) *(u16x8*)&wlds[off] = *(const u16x8*)&wt[off];
  }
  int idC[2]; bool mC[2];
  #pragma unroll
  for (int rt = 0; rt < 2; ++rt){
    idC[rt] = in_idx[rowc[rt]];
    int mv = fInt ? mi32[rowc[rt]] : (int)mu8[rowc[rt]];
    mC[rt] = (mv != 0);
  }
  __syncthreads();

  for (int k = 0; k < KNB; ++k){
    // issue next tap's W into registers (written to LDS after MFMAs)
    u16x8 wpre[SEGS];
    if (k + 1 < KNB){
      const u16* wn = wt + (size_t)(k + 1) * WELE;
      #pragma unroll
      for (int s = 0; s < SEGS; ++s){
        int off = (tid + s * 256) * 8;
        if (off < WELE) wpre[s] = *(const u16x8*)&wn[off];
      }
    }
    // issue next tap's ids/mask
    int idN[2]; bool mN[2];
    if (k + 1 < KNB){
      #pragma unroll
      for (int rt = 0; rt < 2; ++rt){
        idN[rt] = in_idx[(k + 1) * NPT + rowc[rt]];
        int mv = fInt ? mi32[(k + 1) * NPT + rowc[rt]] : (int)mu8[(k + 1) * NPT + rowc[rt]];
        mN[rt] = (mv != 0);
      }
    }

    // gather A[k], exec-masked on validity (invalid lanes: zero traffic)
    bf16x8 a[2][NKC];
    #pragma unroll
    for (int rt = 0; rt < 2; ++rt){
      if (mC[rt]){
        #pragma unroll
        for (int kc = 0; kc < NKC; ++kc){
          int ci0 = kc * 32 + kgrp * 8;
          const u16* ap;
          if (CONCAT) ap = (ci0 < 96) ? (x0 + (size_t)idC[rt] * 96 + ci0)
                                      : (x1 + (size_t)idC[rt] * 96 + (ci0 - 96));
          else        ap = x0 + (size_t)idC[rt] * CIN + ci0;
          a[rt][kc] = *(const bf16x8*)ap;
        }
      } else {
        #pragma unroll
        for (int kc = 0; kc < NKC; ++kc){ bf16x8 z = {}; a[rt][kc] = z; }
      }
    }

    // MFMAs from wbuf[k&1] (frag-order, conflict-free b128)
    const u16* wb = &wlds[(k & 1) * WELE];
    #pragma unroll
    for (int kc = 0; kc < NKC; ++kc){
      #pragma unroll
      for (int cb = 0; cb < NCB; ++cb){
        bf16x8 b = *(const bf16x8*)&wb[((kc * NCB + cb) * 64 + lane) * 8];
        acc[0][cb] = __builtin_amdgcn_mfma_f32_16x16x32_bf16(a[0][kc], b, acc[0][cb], 0, 0, 0);
        acc[1][cb] = __builtin_amdgcn_mfma_f32_16x16x32_bf16(a[1][kc], b, acc[1][cb], 0, 0, 0);
      }
    }

    // write next W into the other buffer (its readers finished at the
    // previous barrier), then ONE barrier per tap
    if (k + 1 < KNB){
      u16* wd = &wlds[((k + 1) & 1) * WELE];
      #pragma unroll
      for (int s = 0; s < SEGS; ++s){
        int off = (tid + s * 256) * 8;
        if (off < WELE) *(u16x8*)&wd[off] = wpre[s];
      }
      #pragma unroll
      for (int rt = 0; rt < 2; ++rt){ idC[rt] = idN[rt]; mC[rt] = mN[rt]; }
    }
    __syncthreads();
  }

  // epilogue: C/D col = lane&15, row = kgrp*4 + j  [m89-verified]
  #pragma unroll
  for (int rt = 0; rt < 2; ++rt){
    #pragma unroll
    for (int cb = 0; cb < NCB; ++cb){
      const int cout = cb * 16 + r16;
      float s = 0.f, q = 0.f;
      #pragma unroll
      for (int j = 0; j < 4; ++j){
        int row = m0 + wv * 32 + rt * 16 + kgrp * 4 + j;
        if (row < NPT){
          float v = acc[rt][cb][j];
          if (F32OUT) ((float*)outp)[(size_t)row * COUTF + cbase + cout] = v;
          else        ((u16*)outp)[(size_t)row * COUTF + cbase + cout] = f2bf(v);
          s += v; q += v * v;
        }
      }
      atomicAdd(&shS[cout], s); atomicAdd(&shQ[cout], q);
    }
  }
  __syncthreads();
  if (tid < COUT_T){
    atomicAdd(&st[cbase + tid],         shS[tid]);
    atomicAdd(&st[COUTF + cbase + tid], shQ[tid]);
  }
}

// --------------------------------------------------------------- BN + ReLU
template<int CCH, bool ISF32>
__global__ void bnrelu_kernel(void* __restrict__ xp, const float* __restrict__ st,
                              const float* __restrict__ gg, const float* __restrict__ bb){
  const float invN = 1.0f / (float)NPT;
  long tot8 = (long)NPT * CCH / 8;
  for (long e8 = (long)blockIdx.x * 256 + threadIdx.x; e8 < tot8; e8 += (long)gridDim.x * 256){
    long e = e8 * 8;
    int c0 = (int)(e % CCH);
    #pragma unroll
    for (int j = 0; j < 8; ++j){
      int c = c0 + j;
      float mu  = st[c] * invN;
      float var = st[CCH + c] * invN - mu * mu;
      float rs  = rsqrtf(var + 1e-5f);
      float x;
      if (ISF32) x = ((float*)xp)[e + j];
      else       x = bf2f(((u16*)xp)[e + j]);
      float y = gg[c] * (x - mu) * rs + bb[c];
      y = y > 0.f ? y : 0.f;
      if (ISF32) ((float*)xp)[e + j] = y;
      else       ((u16*)xp)[e + j] = f2bf(y);
    }
  }
}

// =====================================================================
extern "C" void kernel_launch(void* const* d_in, const int* in_sizes, int n_in,
                              void* d_out, int out_size, void* d_ws, size_t ws_size,
                              hipStream_t stream){
  const float* feat2d = (const float*)d_in[0];
  const float* feat3d = (const float*)d_in[1];
  const int*   links  = (const int*)d_in[2];
  const int*   cmi    = (const int*)d_in[3];
  const int*   cmo    = (const int*)d_in[4];
  const int*   inidx  = (const int*)d_in[5];
  const void*  mask   = d_in[6];
  const float* W1 = (const float*)d_in[7];
  const float* g1 = (const float*)d_in[8];
  const float* b1 = (const float*)d_in[9];
  const float* W2 = (const float*)d_in[10];
  const float* g2 = (const float*)d_in[11];
  const float* b2 = (const float*)d_in[12];
  const float* W3 = (const float*)d_in[13];
  const float* g3 = (const float*)d_in[14];
  const float* b3 = (const float*)d_in[15];

  char* ws = (char*)d_ws;
  u16* X0 = (u16*)(ws + 0);
  u16* ZA = (u16*)(ws + 0);
  u16* F3 = (u16*)(ws + 38400000);
  u16* Z1 = (u16*)(ws + 76800000);
  u16* FT = (u16*)(ws + 76800000);
  u16* WT1  = (u16*)(ws + 106291200);          // 27*192*64 elems
  u16* WT2  = WT1 + 27 * 192 * 64;             // 27*64*96
  u16* WT3a = WT2 + 27 * 64 * 96;              // 27*192*48
  u16* WT3b = WT3a + 27 * 192 * 48;            // 27*192*48
  float* ST  = (float*)(ws + 108281856);
  float* ST1 = ST;            // 128 floats (S|Q)
  float* ST2 = ST + 128;      // 192 floats
  float* ST3 = ST + 320;      // 192 floats
  int*   FLAG = (int*)(ST + 512);

  hipMemsetAsync(ST, 0, 513 * sizeof(float), stream);
  detect_mask_kernel<<<1, 64, 0, stream>>>((const int*)mask, FLAG);
  transpose2d_kernel<<<7200, 256, 0, stream>>>(feat2d, FT);
  wconvert_kernel<<<(27*192*64 + 255)/256, 256, 0, stream>>>(W1, WT1, 192, 64, 64, 0);
  wconvert_kernel<<<(27*64*96  + 255)/256, 256, 0, stream>>>(W2, WT2, 64, 96, 96, 0);
  wconvert_kernel<<<(27*192*48 + 255)/256, 256, 0, stream>>>(W3, WT3a, 192, 48, 96, 0);
  wconvert_kernel<<<(27*192*48 + 255)/256, 256, 0, stream>>>(W3, WT3b, 192, 48, 96, 48);
  stage_a_kernel<<<(NPT*3 + 255)/256, 256, 0, stream>>>(FT, links, cmi, cmo, X0);

  const int nblk = (NPT + 127) / 128;          // 1563
  const uint8_t* m8 = (const uint8_t*)mask;
  const int* m32 = (const int*)mask;

  // layer 1: X0 (N,192) -> Z1 (N,64)
  conv_kernel<192, 64, false, false, false><<<nblk, 256, 0, stream>>>(X0, nullptr, WT1, nullptr, inidx, m8, m32, FLAG, Z1, ST1);
  bnrelu_kernel<64, false><<<2048, 256, 0, stream>>>(Z1, ST1, g1, b1);

  f3convert_kernel<<<((NPT*96/8) + 255)/256, 256, 0, stream>>>(feat3d, F3);

  // layer 2: Z1 (N,64) -> ZA (N,96)
  conv_kernel<64, 96, false, false, false><<<nblk, 256, 0, stream>>>(Z1, nullptr, WT2, nullptr, inidx, m8, m32, FLAG, ZA, ST2);
  bnrelu_kernel<96, false><<<2048, 256, 0, stream>>>(ZA, ST2, g2, b2);

  // layer 3 (col-split): [F3 | H2] (N,192) -> d_out (N,96) f32
  conv_kernel<192, 48, true, true, true><<<2 * nblk, 256, 0, stream>>>(F3, ZA, WT3a, WT3b, inidx, m8, m32, FLAG, d_out, ST3);
  bnrelu_kernel<96, true><<<2048, 256, 0, stream>>>(d_out, ST3, g3, b3);
}

// Round 5
// 763.340 us; speedup vs baseline: 1.3178x; 1.1739x over previous
//
#include <hip/hip_runtime.h>
#include <stdint.h>

// SemsegCDRLink R5: R4 with the sentinel-memset ordering bug fixed.
// (R4's Z1-sentinel memset ran while the region still held FT, corrupting
//  two feature pixels before stage_a read them.)
// 32x32x16 MFMA @64 rows/wave, zero-row sentinel gathers, W staged via
// global_load_lds into frag-order LDS (single buffer, 2 barriers/tap),
// contiguous X3=[F3|H2], fused BN stats.

constexpr int NPT = 200000;   // N voxels
constexpr int KNB = 27;       // kernel taps

typedef unsigned short u16;
typedef __attribute__((ext_vector_type(8))) short     bf16x8;
typedef __attribute__((ext_vector_type(8))) unsigned short u16x8;
typedef __attribute__((ext_vector_type(16))) float    f32x16;

static __device__ __forceinline__ u16 f2bf(float f){
  unsigned int u = __float_as_uint(f);
  unsigned int r = (u + 0x7fffu + ((u >> 16) & 1u)) >> 16;
  return (u16)r;
}
static __device__ __forceinline__ float bf2f(u16 u){
  return __uint_as_float(((unsigned int)u) << 16);
}

// global -> LDS direct copy, 16B per lane; lds dest is wave-uniform base.
static __device__ __forceinline__ void gload_lds16(const void* g, void* l){
  __builtin_amdgcn_global_load_lds(
      (const __attribute__((address_space(1))) void*)g,
      (__attribute__((address_space(3))) void*)(uint32_t)(uintptr_t)l,
      16, 0, 0);
}

// ---------------------------------------------------------------- mask dtype
__global__ void detect_mask_kernel(const int* __restrict__ m32, int* __restrict__ flag){
  if (threadIdx.x == 0 && blockIdx.x == 0){
    int ok = 1;
    for (int i = 0; i < 64; ++i){ int v = m32[i]; if (v != 0 && v != 1) ok = 0; }
    *flag = ok;   // 1 => int32 masks, 0 => uint8 masks
  }
}

// ------------------------------------------------- feat_2d transpose to NHWC
__global__ __launch_bounds__(256) void transpose2d_kernel(const float* __restrict__ in,
                                                          u16* __restrict__ out){
  __shared__ float tile[64][33];
  int bid = blockIdx.x;
  int wt = bid % 5;  int rest = bid / 5;
  int h  = rest % 120; rest /= 120;
  int b  = rest % 4;  int v = rest / 4;
  int w0 = wt * 32;
  int tx = threadIdx.x & 31;
  int ty = threadIdx.x >> 5;
  const float* ip = in + ((size_t)(v*4 + b) * 64) * 19200 + h * 160 + w0;
  #pragma unroll
  for (int cc = 0; cc < 8; ++cc){
    int c = cc * 8 + ty;
    tile[c][tx] = ip[(size_t)c * 19200 + tx];
  }
  __syncthreads();
  u16* op = out + (((size_t)(v*4 + b) * 120 + h) * 160 + w0) * 64;
  int c = threadIdx.x & 63;
  int wg = threadIdx.x >> 6;
  #pragma unroll
  for (int i = 0; i < 8; ++i){
    int w = wg + i * 4;
    op[(size_t)w * 64 + c] = f2bf(tile[c][w]);
  }
}

// ------------------------------------------------------------ weight reshape
// src: [K][cin][cout] f32 -> frag order for 32x32x16:
// dst[((k*NKS+ks)*NCB+cb)*512 + lane*8 + e] =
//   W[k][ks*16+(lane>>5)*8+e][cb*32+(lane&31)]
__global__ void wconvert_kernel(const float* __restrict__ src, u16* __restrict__ dst,
                                int cin, int cout){
  int gid = blockIdx.x * 256 + threadIdx.x;
  int wele = cin * cout;
  int tot = KNB * wele;
  if (gid >= tot) return;
  int ncb = cout / 32;
  int nks = cin / 16;
  int e    = gid & 7;
  int lane = (gid >> 3) & 63;
  int f    = gid >> 9;
  int cb   = f % ncb;  f /= ncb;
  int ks   = f % nks;
  int k    = f / nks;
  int ci = ks * 16 + (lane >> 5) * 8 + e;
  int co = cb * 32 + (lane & 31);
  dst[gid] = f2bf(src[((size_t)k * cin + ci) * cout + co]);
}

// --------------------------------------------------------------- 2D->3D gather
__global__ void stage_a_kernel(const u16* __restrict__ ft, const int* __restrict__ links,
                               const int* __restrict__ cmi, const int* __restrict__ cmo,
                               u16* __restrict__ x0){
  int gid = blockIdx.x * 256 + threadIdx.x;
  if (gid >= NPT * 3) return;
  int i = gid / 3;
  int v = gid - i * 3;
  int outr = cmo[i];
  int l    = cmi[i];
  int b  = links[l*12 + v];
  int h  = links[l*12 + 3 + v];
  int w  = links[l*12 + 6 + v];
  int vl = links[l*12 + 9 + v];
  u16* dst = x0 + (size_t)outr * 192 + v * 64;
  if (vl){
    const u16* src = ft + (((size_t)(v*4 + b) * 120 + h) * 160 + w) * 64;
    #pragma unroll
    for (int j = 0; j < 8; ++j) ((u16x8*)dst)[j] = ((const u16x8*)src)[j];
  } else {
    u16x8 z = {};
    #pragma unroll
    for (int j = 0; j < 8; ++j) ((u16x8*)dst)[j] = z;
  }
}

// --------------------------------- feat3d f32 -> X3 cols [0,96) (stride 192)
__global__ void f3convert_kernel(const float* __restrict__ src, u16* __restrict__ dst){
  long gid = (long)blockIdx.x * 256 + threadIdx.x;
  long tot8 = (long)NPT * 12;           // 96/8 groups per row
  if (gid >= tot8) return;
  int row = (int)(gid / 12);
  int c0  = (int)(gid % 12) * 8;
  const float* s = src + (size_t)row * 96 + c0;
  u16* d = dst + (size_t)row * 192 + c0;
  #pragma unroll
  for (int j = 0; j < 8; ++j) d[j] = f2bf(s[j]);
}

// ------------------------------------------------------------------ conv core
// 256 thr = 4 waves, 256 rows/block (64 rows/wave = 2 row-tiles of 32).
// Sentinel gathers: vidx = mask ? idx : NPT (row NPT is zeroed).
// W[k] in LDS frag-order via global_load_lds; 2 barriers/tap.
template<int CIN, int COUT, bool F32OUT>
__global__ __launch_bounds__(256)
void conv_kernel(const u16* __restrict__ x0, const u16* __restrict__ wt,
                 const int* __restrict__ in_idx,
                 const uint8_t* __restrict__ mu8, const int* __restrict__ mi32,
                 const int* __restrict__ flagp, void* __restrict__ outp,
                 int outStride, float* __restrict__ st){
  constexpr int NCB    = COUT / 32;
  constexpr int NKC    = CIN / 16;
  constexpr int WELE   = CIN * COUT;          // u16 elems per tap
  constexpr int ROUNDS = (WELE * 2) / 4096;   // staging rounds (4 waves x 1KB)
  __shared__ __align__(16) u16 wlds[WELE];
  __shared__ float shS[COUT], shQ[COUT];

  const int tid   = threadIdx.x;
  const int lane  = tid & 63;
  const int wv    = tid >> 6;
  const int l31   = lane & 31;
  const int khalf = lane >> 5;
  const int m0    = blockIdx.x * 256;
  const int fInt  = *flagp;

  if (tid < COUT){ shS[tid] = 0.f; shQ[tid] = 0.f; }

  f32x16 acc[2][NCB];
  #pragma unroll
  for (int rt = 0; rt < 2; ++rt)
    #pragma unroll
    for (int cb = 0; cb < NCB; ++cb) acc[rt][cb] = (f32x16)0.0f;

  int rowc[2];
  #pragma unroll
  for (int rt = 0; rt < 2; ++rt){
    int row = m0 + wv * 64 + rt * 32 + l31;
    rowc[rt] = row < NPT ? row : NPT - 1;
  }

  // prologue: stage W[0], load fused vidx[0]
  #pragma unroll
  for (int rd = 0; rd < ROUNDS; ++rd){
    int chunk = rd * 4 + wv;
    gload_lds16((const char*)wt + chunk * 1024 + lane * 16,
                (char*)wlds + chunk * 1024);
  }
  int vC[2];
  #pragma unroll
  for (int rt = 0; rt < 2; ++rt){
    int id = in_idx[rowc[rt]];
    int mv; if (fInt) mv = mi32[rowc[rt]]; else mv = (int)mu8[rowc[rt]];
    vC[rt] = mv ? id : NPT;
  }
  __syncthreads();

  const u16* xk = x0 + khalf * 8;   // fold khalf offset into base

  for (int k = 0; k < KNB; ++k){
    // gather bases for tap k
    const u16* b0 = xk + (size_t)vC[0] * CIN;
    const u16* b1 = xk + (size_t)vC[1] * CIN;

    // prefetch fused vidx[k+1]
    if (k + 1 < KNB){
      #pragma unroll
      for (int rt = 0; rt < 2; ++rt){
        int o = (k + 1) * NPT + rowc[rt];
        int id = in_idx[o];
        int mv; if (fInt) mv = mi32[o]; else mv = (int)mu8[o];
        vC[rt] = mv ? id : NPT;
      }
    }

    // MFMAs: A gathered (imm-offset loads), B from frag-order LDS
    #pragma unroll
    for (int kc = 0; kc < NKC; ++kc){
      bf16x8 a0 = *(const bf16x8*)(b0 + kc * 16);
      bf16x8 a1 = *(const bf16x8*)(b1 + kc * 16);
      #pragma unroll
      for (int cb = 0; cb < NCB; ++cb){
        bf16x8 b = *(const bf16x8*)&wlds[((kc * NCB + cb) * 64 + lane) * 8];
        acc[0][cb] = __builtin_amdgcn_mfma_f32_32x32x16_bf16(a0, b, acc[0][cb], 0, 0, 0);
        acc[1][cb] = __builtin_amdgcn_mfma_f32_32x32x16_bf16(a1, b, acc[1][cb], 0, 0, 0);
      }
    }
    __syncthreads();                       // all wlds reads done

    if (k + 1 < KNB){
      const u16* wn = wt + (size_t)(k + 1) * WELE;
      #pragma unroll
      for (int rd = 0; rd < ROUNDS; ++rd){
        int chunk = rd * 4 + wv;
        gload_lds16((const char*)wn + chunk * 1024 + lane * 16,
                    (char*)wlds + chunk * 1024);
      }
    }
    __syncthreads();                       // publish W[k+1] (vmcnt drained)
  }

  // epilogue: C/D col = lane&31, row = (r&3)+8*(r>>2)+4*khalf  [R2-verified]
  #pragma unroll
  for (int rt = 0; rt < 2; ++rt){
    #pragma unroll
    for (int cb = 0; cb < NCB; ++cb){
      const int cout = cb * 32 + l31;
      float s = 0.f, q = 0.f;
      #pragma unroll
      for (int r = 0; r < 16; ++r){
        int row = m0 + wv * 64 + rt * 32 + (r & 3) + 8 * (r >> 2) + 4 * khalf;
        if (row < NPT){
          float v = acc[rt][cb][r];
          if (F32OUT) ((float*)outp)[(size_t)row * outStride + cout] = v;
          else        ((u16*)outp)[(size_t)row * outStride + cout] = f2bf(v);
          s += v; q += v * v;
        }
      }
      atomicAdd(&shS[cout], s); atomicAdd(&shQ[cout], q);
    }
  }
  __syncthreads();
  if (tid < COUT){
    atomicAdd(&st[tid],        shS[tid]);
    atomicAdd(&st[COUT + tid], shQ[tid]);
  }
}

// --------------------------------------------------------------- BN + ReLU
// operates on CCH cols of a row-strided buffer (base already at col offset)
template<int CCH, bool ISF32>
__global__ void bnrelu_kernel(void* __restrict__ xp, int stride,
                              const float* __restrict__ st,
                              const float* __restrict__ gg, const float* __restrict__ bb){
  const float invN = 1.0f / (float)NPT;
  constexpr int GPR = CCH / 8;
  long tot8 = (long)NPT * GPR;
  for (long e8 = (long)blockIdx.x * 256 + threadIdx.x; e8 < tot8; e8 += (long)gridDim.x * 256){
    int row = (int)(e8 / GPR);
    int c0  = (int)(e8 % GPR) * 8;
    size_t base = (size_t)row * stride + c0;
    #pragma unroll
    for (int j = 0; j < 8; ++j){
      int c = c0 + j;
      float mu  = st[c] * invN;
      float var = st[CCH + c] * invN - mu * mu;
      float rs  = rsqrtf(var + 1e-5f);
      float x;
      if (ISF32) x = ((float*)xp)[base + j];
      else       x = bf2f(((u16*)xp)[base + j]);
      float y = gg[c] * (x - mu) * rs + bb[c];
      y = y > 0.f ? y : 0.f;
      if (ISF32) ((float*)xp)[base + j] = y;
      else       ((u16*)xp)[base + j] = f2bf(y);
    }
  }
}

// =====================================================================
extern "C" void kernel_launch(void* const* d_in, const int* in_sizes, int n_in,
                              void* d_out, int out_size, void* d_ws, size_t ws_size,
                              hipStream_t stream){
  const float* feat2d = (const float*)d_in[0];
  const float* feat3d = (const float*)d_in[1];
  const int*   links  = (const int*)d_in[2];
  const int*   cmi    = (const int*)d_in[3];
  const int*   cmo    = (const int*)d_in[4];
  const int*   inidx  = (const int*)d_in[5];
  const void*  mask   = d_in[6];
  const float* W1 = (const float*)d_in[7];
  const float* g1 = (const float*)d_in[8];
  const float* b1 = (const float*)d_in[9];
  const float* W2 = (const float*)d_in[10];
  const float* g2 = (const float*)d_in[11];
  const float* b2 = (const float*)d_in[12];
  const float* W3 = (const float*)d_in[13];
  const float* g3 = (const float*)d_in[14];
  const float* b3 = (const float*)d_in[15];

  // ws layout (bytes), high-water ~108.3 MB:
  //  [0, 76.80M)           X0 (N+1,192)bf16 ; reused as X3=[F3|H2] (N+1,192)
  //  [76.80M, 106.29M)     FT (29.5M) ; after stage_a reused as Z1 (N+1,64)
  //  [106.29M, 108.28M)    WT1|WT2|WT3 bf16 frag order
  //  [108.28M, ...)        stats (512 f32) + flag
  char* ws = (char*)d_ws;
  u16* X0 = (u16*)(ws + 0);                    // also X3
  constexpr size_t OFF_B  = 76800512;
  u16* FT = (u16*)(ws + OFF_B);
  u16* Z1 = (u16*)(ws + OFF_B);
  u16* WT1 = (u16*)(ws + 106291712);           // 27*192*64 elems
  u16* WT2 = WT1 + 27 * 192 * 64;              // 27*64*96
  u16* WT3 = WT2 + 27 * 64 * 96;               // 27*192*96
  float* ST  = (float*)(ws + 108282368);
  float* ST1 = ST;            // 128 floats (S|Q)
  float* ST2 = ST + 128;      // 192 floats
  float* ST3 = ST + 320;      // 192 floats
  int*   FLAG = (int*)(ST + 512);

  hipMemsetAsync(ST, 0, 513 * sizeof(float), stream);
  detect_mask_kernel<<<1, 64, 0, stream>>>((const int*)mask, FLAG);
  transpose2d_kernel<<<7200, 256, 0, stream>>>(feat2d, FT);
  wconvert_kernel<<<(27*192*64 + 255)/256, 256, 0, stream>>>(W1, WT1, 192, 64);
  wconvert_kernel<<<(27*64*96  + 255)/256, 256, 0, stream>>>(W2, WT2, 64, 96);
  wconvert_kernel<<<(27*192*96 + 255)/256, 256, 0, stream>>>(W3, WT3, 192, 96);
  stage_a_kernel<<<(NPT*3 + 255)/256, 256, 0, stream>>>(FT, links, cmi, cmo, X0);

  // Sentinel rows — AFTER stage_a (FT is dead now; R4 zeroed these while the
  // Z1 region still held FT, corrupting two feature pixels => absmax 3.5).
  // X0/X3 row NPT (384B) and Z1 row NPT (128B); no kernel writes row NPT,
  // so they stay zero through the launch and across graph replays.
  hipMemsetAsync(ws + (size_t)NPT * 384, 0, 384, stream);
  hipMemsetAsync(ws + OFF_B + (size_t)NPT * 128, 0, 128, stream);

  const int nblk = (NPT + 255) / 256;          // 782
  const uint8_t* m8 = (const uint8_t*)mask;
  const int* m32 = (const int*)mask;

  // layer 1: X0 (N,192) -> Z1 (N,64)          [Z1 overwrites FT]
  conv_kernel<192, 64, false><<<nblk, 256, 0, stream>>>(X0, WT1, inidx, m8, m32, FLAG, Z1, 64, ST1);
  bnrelu_kernel<64, false><<<2048, 256, 0, stream>>>(Z1, 64, ST1, g1, b1);

  // build X3: cols [0,96) = bf16(feat3d)      [overwrites X0 after conv1]
  f3convert_kernel<<<((NPT*12) + 255)/256, 256, 0, stream>>>(feat3d, X0);

  // layer 2: Z1 (N,64) -> X3 cols [96,192)
  conv_kernel<64, 96, false><<<nblk, 256, 0, stream>>>(Z1, WT2, inidx, m8, m32, FLAG, X0 + 96, 192, ST2);
  bnrelu_kernel<96, false><<<2048, 256, 0, stream>>>(X0 + 96, 192, ST2, g2, b2);

  // layer 3: X3 (N,192) -> d_out (N,96) f32
  conv_kernel<192, 96, true><<<nblk, 256, 0, stream>>>(X0, WT3, inidx, m8, m32, FLAG, d_out, 96, ST3);
  bnrelu_kernel<96, true><<<2048, 256, 0, stream>>>(d_out, 96, ST3, g3, b3);
}